// Round 2
// baseline (2561.816 us; speedup 1.0000x reference)
//
#include <hip/hip_runtime.h>
#include <cfloat>

// Problem constants
#define B_SZ 8
#define N_SZ 2048
#define D_SZ 512
#define K_SZ 8192
#define M_SZ (B_SZ * N_SZ)  // 16384

#define DECAY_F 0.99f
#define OMD_F ((float)(1.0 - 0.99))  // one-minus-decay, rounded to f32
#define EPS_F 1e-5f

// Output layout (flat float offsets, reference return order)
#define OUT1_OFF 8388608   // indices (B*N) as float
#define OUT2_OFF 8404992   // commitment loss (1)
#define OUT3_OFF 8404993   // new_ema_cluster_sizes (K)
#define OUT4_OFF 8413185   // new_ema_codebook (K*D)
#define OUT5_OFF 12607489  // new_embedding (K*D)

// Argmin-GEMM tiling
#define BM 128
#define BN 128
#define DKC 32
#define NSPLIT 8
#define KSPLIT (K_SZ / NSPLIT)  // 1024 cols per block
#define CT (KSPLIT / BN)        // 8 col-tiles per block
#define LDP (BM + 4)            // padded LDS row stride (132 floats, 16B-aligned)

// ---------------- e_sq: per-codebook-row squared norm ----------------
__global__ __launch_bounds__(256) void k_esq(const float* __restrict__ e,
                                             float* __restrict__ esq) {
    int row = blockIdx.x * 4 + (threadIdx.x >> 6);
    int lane = threadIdx.x & 63;
    const float4* er = (const float4*)(e + (size_t)row * D_SZ);
    float s = 0.f;
#pragma unroll
    for (int i = 0; i < 2; ++i) {
        float4 v = er[lane + i * 64];
        s += v.x * v.x + v.y * v.y + v.z * v.z + v.w * v.w;
    }
#pragma unroll
    for (int off = 32; off; off >>= 1) s += __shfl_down(s, off);
    if (lane == 0) esq[row] = s;
}

// ---------------- init: out4 = 0.99*codebook, out3 = 0.99*sizes ------
__global__ __launch_bounds__(256) void k_init(const float* __restrict__ cb,
                                              const float* __restrict__ sizes,
                                              float* __restrict__ out3,
                                              float* __restrict__ out4) {
    int i = blockIdx.x * 256 + threadIdx.x;  // grid covers K*D exactly
    out4[i] = cb[i] * DECAY_F;
    if (i < K_SZ) out3[i] = sizes[i] * DECAY_F;
}

// ---------------- copy: quantized_ste == encoded_latents -------------
__global__ __launch_bounds__(256) void k_copy(const float* __restrict__ z,
                                              float* __restrict__ out0) {
    int i = blockIdx.x * 256 + threadIdx.x;  // grid covers M*D/4 exactly
    ((float4*)out0)[i] = ((const float4*)z)[i];
}

// ---------------- argmin distance GEMM -------------------------------
// grid = (M/BM, NSPLIT); block = 256 threads; 8x8 accumulators/thread.
// Thread (ty,tx) owns rows ty*8..ty*8+7 and cols {tx*4..+3, 64+tx*4..+3}.
// LDS reads: a = 2x ds_read_b128 (banks ty*8.. distinct, bcast x16, free);
//            b = 2x ds_read_b128 at 16B stride over 16 tx -> 2-way (free).
// z-tile prefetched into registers during previous tile's compute.
__global__ __launch_bounds__(256) void k_argmin(const float* __restrict__ z,
                                                const float* __restrict__ e,
                                                const float* __restrict__ esq,
                                                float* __restrict__ candB,
                                                int* __restrict__ candI) {
    __shared__ float zs[DKC][LDP];
    __shared__ float es[DKC][LDP];

    const int tid = threadIdx.x;
    const int ty = tid >> 4;   // 0..15 -> 8 rows each
    const int tx = tid & 15;   // 0..15 -> 8 cols each (two groups of 4)
    const int row0 = blockIdx.x * BM;
    const int cbase = blockIdx.y * KSPLIT;

    // staging mapping: thread loads rows sm+32i (i=0..3) at k-offset sk..sk+3
    const int sm = tid >> 3;         // 0..31
    const int sk = (tid & 7) * 4;    // 0,4,..,28

    float best[8];
    int bidx[8];
#pragma unroll
    for (int m = 0; m < 8; ++m) { best[m] = FLT_MAX; bidx[m] = 0; }

    float4 zr[4];
    // initial z prefetch (ct=0, d0=0)
#pragma unroll
    for (int i = 0; i < 4; ++i)
        zr[i] = *(const float4*)(z + (size_t)(row0 + sm + 32 * i) * D_SZ + sk);

    for (int ct = 0; ct < CT; ++ct) {
        const int col0 = cbase + ct * BN;
        float acc[8][8];
#pragma unroll
        for (int m = 0; m < 8; ++m)
#pragma unroll
            for (int n = 0; n < 8; ++n) acc[m][n] = 0.f;

        for (int dk = 0; dk < D_SZ / DKC; ++dk) {
            const int d0 = dk * DKC;
            __syncthreads();  // previous compute done reading LDS
            // store phase: z from prefetched regs; e loaded directly
#pragma unroll
            for (int i = 0; i < 4; ++i) {
                const int m = sm + 32 * i;
                float4 w = *(const float4*)(e + (size_t)(col0 + m) * D_SZ + d0 + sk);
                zs[sk + 0][m] = zr[i].x;
                zs[sk + 1][m] = zr[i].y;
                zs[sk + 2][m] = zr[i].z;
                zs[sk + 3][m] = zr[i].w;
                es[sk + 0][m] = w.x;
                es[sk + 1][m] = w.y;
                es[sk + 2][m] = w.z;
                es[sk + 3][m] = w.w;
            }
            __syncthreads();
            // prefetch z for the NEXT tile (hidden under compute below)
            if (!(ct == CT - 1 && dk == D_SZ / DKC - 1)) {
                const int nd0 = (dk < D_SZ / DKC - 1) ? d0 + DKC : 0;
#pragma unroll
                for (int i = 0; i < 4; ++i)
                    zr[i] = *(const float4*)(z + (size_t)(row0 + sm + 32 * i) * D_SZ + nd0 + sk);
            }
            // compute
#pragma unroll
            for (int kk = 0; kk < DKC; ++kk) {
                float a[8], b[8];
                *(float4*)&a[0] = *(const float4*)&zs[kk][ty * 8];
                *(float4*)&a[4] = *(const float4*)&zs[kk][ty * 8 + 4];
                *(float4*)&b[0] = *(const float4*)&es[kk][tx * 4];
                *(float4*)&b[4] = *(const float4*)&es[kk][64 + tx * 4];
#pragma unroll
                for (int m = 0; m < 8; ++m)
#pragma unroll
                    for (int n = 0; n < 8; ++n)
                        acc[m][n] = fmaf(a[m], b[n], acc[m][n]);
            }
        }
        // epilogue: dist = e_sq - 2*dot (z_sq row-constant, argmin-invariant)
        // scan columns in ascending order; strict < keeps lowest index on ties
#pragma unroll
        for (int h = 0; h < 2; ++h)
#pragma unroll
            for (int n = 0; n < 4; ++n) {
                const int col = col0 + h * 64 + tx * 4 + n;
                const float eq = esq[col];
#pragma unroll
                for (int m = 0; m < 8; ++m) {
                    float dist = fmaf(-2.0f, acc[m][h * 4 + n], eq);
                    if (dist < best[m]) { best[m] = dist; bidx[m] = col; }
                }
            }
    }

    // reduce across the 16 tx lanes (same ty = 16 consecutive lanes in a wave)
#pragma unroll
    for (int off = 1; off < 16; off <<= 1) {
#pragma unroll
        for (int m = 0; m < 8; ++m) {
            float ob = __shfl_xor(best[m], off);
            int oi = __shfl_xor(bidx[m], off);
            if (ob < best[m] || (ob == best[m] && oi < bidx[m])) {
                best[m] = ob;
                bidx[m] = oi;
            }
        }
    }
    if (tx == 0) {
#pragma unroll
        for (int m = 0; m < 8; ++m) {
            int row = row0 + ty * 8 + m;
            candB[row * NSPLIT + blockIdx.y] = best[m];
            candI[row * NSPLIT + blockIdx.y] = bidx[m];
        }
    }
}

// ---------------- merge the NSPLIT candidates per row ----------------
__global__ __launch_bounds__(256) void k_merge(const float* __restrict__ candB,
                                               const int* __restrict__ candI,
                                               int* __restrict__ nearest,
                                               float* __restrict__ out1) {
    int row = blockIdx.x * 256 + threadIdx.x;  // grid covers M exactly
    float b = FLT_MAX;
    int bi = 0;
#pragma unroll
    for (int s = 0; s < NSPLIT; ++s) {
        float v = candB[row * NSPLIT + s];
        int i = candI[row * NSPLIT + s];
        if (v < b || (v == b && i < bi)) { b = v; bi = i; }
    }
    nearest[row] = bi;
    out1[row] = (float)bi;
}

// ---------------- scatter: EMA accumulate + commitment loss ----------
__global__ __launch_bounds__(256) void k_scatter(const float* __restrict__ z,
                                                 const float* __restrict__ e,
                                                 const int* __restrict__ nearest,
                                                 float* __restrict__ out3,
                                                 float* __restrict__ out4,
                                                 float* __restrict__ lossAcc) {
    const int tid = threadIdx.x;  // 256 threads, each handles 2 elems/row
    float lp = 0.f;
    const int base_row = blockIdx.x * 8;
#pragma unroll
    for (int r = 0; r < 8; ++r) {
        int row = base_row + r;
        int n = nearest[row];
        float2 zv = ((const float2*)(z + (size_t)row * D_SZ))[tid];
        float2 ev = ((const float2*)(e + (size_t)n * D_SZ))[tid];
        float* o4 = out4 + (size_t)n * D_SZ + tid * 2;
        atomicAdd(o4, OMD_F * zv.x);
        atomicAdd(o4 + 1, OMD_F * zv.y);
        float dx = zv.x - ev.x, dy = zv.y - ev.y;
        lp += dx * dx + dy * dy;
        if (tid == 0) atomicAdd(out3 + n, OMD_F);
    }
#pragma unroll
    for (int off = 32; off; off >>= 1) lp += __shfl_down(lp, off);
    __shared__ float red[4];
    if ((tid & 63) == 0) red[tid >> 6] = lp;
    __syncthreads();
    if (tid == 0) atomicAdd(lossAcc, red[0] + red[1] + red[2] + red[3]);
}

// ---------------- finalize: new_embedding + loss scalar --------------
__global__ __launch_bounds__(256) void k_final(const float* __restrict__ out3,
                                               const float* __restrict__ out4,
                                               float* __restrict__ out5,
                                               const float* __restrict__ lossAcc,
                                               float* __restrict__ out2) {
    int i = blockIdx.x * 256 + threadIdx.x;  // grid covers K*D exactly
    out5[i] = out4[i] / (out3[i >> 9] + EPS_F);
    if (i == 0) out2[0] = 0.25f * lossAcc[0] / 8388608.0f;
}

extern "C" void kernel_launch(void* const* d_in, const int* in_sizes, int n_in,
                              void* d_out, int out_size, void* d_ws, size_t ws_size,
                              hipStream_t stream) {
    const float* z = (const float*)d_in[0];      // encoded_latents (B*N, D)
    const float* ew = (const float*)d_in[1];     // embedding_weight (K, D)
    const float* sizes = (const float*)d_in[2];  // ema_cluster_sizes (K)
    const float* cb = (const float*)d_in[3];     // ema_codebook (K, D)

    float* out = (float*)d_out;
    float* out0 = out;             // quantized_ste == encoded_latents
    float* out1 = out + OUT1_OFF;  // indices (float)
    float* out2 = out + OUT2_OFF;  // loss
    float* out3 = out + OUT3_OFF;  // new_ema_cluster_sizes
    float* out4 = out + OUT4_OFF;  // new_ema_codebook
    float* out5 = out + OUT5_OFF;  // new_embedding

    // small scratch in ws
    int* nearest = (int*)d_ws;                      // 16384 ints
    float* esq = (float*)d_ws + M_SZ;               // 8192 floats
    float* lossAcc = (float*)d_ws + M_SZ + K_SZ;    // 1 float

    // argmin candidates staged in out5 (overwritten by k_final afterwards)
    float* candB = out5;                            // 16384*8 floats
    int* candI = (int*)(out5 + M_SZ * NSPLIT);      // 16384*8 ints

    hipMemsetAsync(lossAcc, 0, sizeof(float), stream);

    k_esq<<<K_SZ / 4, 256, 0, stream>>>(ew, esq);
    k_init<<<(K_SZ * D_SZ) / 256, 256, 0, stream>>>(cb, sizes, out3, out4);
    k_copy<<<(M_SZ * D_SZ / 4) / 256, 256, 0, stream>>>(z, out0);

    dim3 ag(M_SZ / BM, NSPLIT);
    k_argmin<<<ag, 256, 0, stream>>>(z, ew, esq, candB, candI);
    k_merge<<<M_SZ / 256, 256, 0, stream>>>(candB, candI, nearest, out1);
    k_scatter<<<M_SZ / 8, 256, 0, stream>>>(z, ew, nearest, out3, out4, lossAcc);
    k_final<<<(K_SZ * D_SZ) / 256, 256, 0, stream>>>(out3, out4, out5, lossAcc, out2);
}

// Round 3
// 1707.987 us; speedup vs baseline: 1.4999x; 1.4999x over previous
//
#include <hip/hip_runtime.h>
#include <cfloat>

// Problem constants
#define B_SZ 8
#define N_SZ 2048
#define D_SZ 512
#define K_SZ 8192
#define M_SZ (B_SZ * N_SZ)  // 16384

#define DECAY_F 0.99f
#define OMD_F ((float)(1.0 - 0.99))  // one-minus-decay, rounded to f32
#define EPS_F 1e-5f

// Output layout (flat float offsets, reference return order)
#define OUT1_OFF 8388608   // indices (B*N) as float
#define OUT2_OFF 8404992   // commitment loss (1)
#define OUT3_OFF 8404993   // new_ema_cluster_sizes (K)
#define OUT4_OFF 8413185   // new_ema_codebook (K*D)
#define OUT5_OFF 12607489  // new_embedding (K*D)

// Argmin-GEMM tiling
#define BM 128
#define BN 128
#define DKC 32
#define NSPLIT 8
#define KSPLIT (K_SZ / NSPLIT)  // 1024 cols per block
#define CT (KSPLIT / BN)        // 8 col-tiles per block

// ---------------- e_sq: per-codebook-row squared norm ----------------
__global__ __launch_bounds__(256) void k_esq(const float* __restrict__ e,
                                             float* __restrict__ esq) {
    int row = blockIdx.x * 4 + (threadIdx.x >> 6);
    int lane = threadIdx.x & 63;
    const float4* er = (const float4*)(e + (size_t)row * D_SZ);
    float s = 0.f;
#pragma unroll
    for (int i = 0; i < 2; ++i) {
        float4 v = er[lane + i * 64];
        s += v.x * v.x + v.y * v.y + v.z * v.z + v.w * v.w;
    }
#pragma unroll
    for (int off = 32; off; off >>= 1) s += __shfl_down(s, off);
    if (lane == 0) esq[row] = s;
}

// ---------------- init: out4 = 0.99*codebook, out3 = 0.99*sizes ------
__global__ __launch_bounds__(256) void k_init(const float* __restrict__ cb,
                                              const float* __restrict__ sizes,
                                              float* __restrict__ out3,
                                              float* __restrict__ out4) {
    int i = blockIdx.x * 256 + threadIdx.x;  // grid covers K*D exactly
    out4[i] = cb[i] * DECAY_F;
    if (i < K_SZ) out3[i] = sizes[i] * DECAY_F;
}

// ---------------- copy: quantized_ste == encoded_latents -------------
__global__ __launch_bounds__(256) void k_copy(const float* __restrict__ z,
                                              float* __restrict__ out0) {
    int i = blockIdx.x * 256 + threadIdx.x;  // grid covers M*D/4 exactly
    ((float4*)out0)[i] = ((const float4*)z)[i];
}

// ---------------- argmin distance GEMM -------------------------------
// grid = (M/BM, NSPLIT); block = 256 threads; 8x8 accumulators/thread.
// LDS tiles are [k][m] with column XOR-swizzle: phys_col = m ^ (((k>>2)&3)<<3).
//   writes: bank = sm + 8*(tid&3) -> 32 banks x 2 lanes (2-way = free)
//   reads:  kk compile-time -> swizzle constant-folds; a-reads broadcast,
//           b-reads 16x b128 XOR-permuted over 256B (2-way = free)
__global__ __launch_bounds__(256, 4) void k_argmin(const float* __restrict__ z,
                                                   const float* __restrict__ e,
                                                   const float* __restrict__ esq,
                                                   float* __restrict__ candB,
                                                   int* __restrict__ candI) {
    __shared__ float zs[DKC][BM];
    __shared__ float es[DKC][BN];

    const int tid = threadIdx.x;
    const int ty = tid >> 4;   // 0..15 -> 8 rows each
    const int tx = tid & 15;   // 0..15 -> 8 cols each (two groups of 4)
    const int row0 = blockIdx.x * BM;
    const int cbase = blockIdx.y * KSPLIT;

    // staging mapping: thread loads rows sm+32i (i=0..3) at k-offset sk..sk+3
    const int sm = tid >> 3;         // 0..31
    const int sk = (tid & 7) * 4;    // 0,4,..,28
    const int gw = (tid & 3) << 3;   // = ((k>>2)&3)<<3 for k in [sk, sk+3]

    float best[8];
    int bidx[8];
#pragma unroll
    for (int m = 0; m < 8; ++m) { best[m] = FLT_MAX; bidx[m] = 0; }

    for (int ct = 0; ct < CT; ++ct) {
        const int col0 = cbase + ct * BN;
        float acc[8][8];
#pragma unroll
        for (int m = 0; m < 8; ++m)
#pragma unroll
            for (int n = 0; n < 8; ++n) acc[m][n] = 0.f;

        for (int dk = 0; dk < D_SZ / DKC; ++dk) {
            const int d0 = dk * DKC;
            __syncthreads();  // previous compute done reading LDS
#pragma unroll
            for (int i = 0; i < 4; ++i) {
                const int m = sm + 32 * i;
                const int pc = m ^ gw;  // swizzled physical column
                float4 v = *(const float4*)(z + (size_t)(row0 + m) * D_SZ + d0 + sk);
                float4 w = *(const float4*)(e + (size_t)(col0 + m) * D_SZ + d0 + sk);
                zs[sk + 0][pc] = v.x;
                zs[sk + 1][pc] = v.y;
                zs[sk + 2][pc] = v.z;
                zs[sk + 3][pc] = v.w;
                es[sk + 0][pc] = w.x;
                es[sk + 1][pc] = w.y;
                es[sk + 2][pc] = w.z;
                es[sk + 3][pc] = w.w;
            }
            __syncthreads();
            // compute (kk compile-time -> swizzle XORs fold to constants)
#pragma unroll
            for (int kk = 0; kk < DKC; ++kk) {
                const int gr = ((kk >> 2) & 3) << 3;
                float a[8], b[8];
                *(float4*)&a[0] = *(const float4*)&zs[kk][(ty * 8) ^ gr];
                *(float4*)&a[4] = *(const float4*)&zs[kk][(ty * 8 + 4) ^ gr];
                *(float4*)&b[0] = *(const float4*)&es[kk][(tx * 4) ^ gr];
                *(float4*)&b[4] = *(const float4*)&es[kk][(64 + tx * 4) ^ gr];
#pragma unroll
                for (int m = 0; m < 8; ++m)
#pragma unroll
                    for (int n = 0; n < 8; ++n)
                        acc[m][n] = fmaf(a[m], b[n], acc[m][n]);
            }
        }
        // epilogue: dist = e_sq - 2*dot (z_sq row-constant, argmin-invariant)
        // ascending column order within each half; halves are disjoint ranges
#pragma unroll
        for (int h = 0; h < 2; ++h)
#pragma unroll
            for (int n = 0; n < 4; ++n) {
                const int col = col0 + h * 64 + tx * 4 + n;
                const float eq = esq[col];
#pragma unroll
                for (int m = 0; m < 8; ++m) {
                    float dist = fmaf(-2.0f, acc[m][h * 4 + n], eq);
                    if (dist < best[m]) { best[m] = dist; bidx[m] = col; }
                }
            }
    }

    // reduce across the 16 tx lanes (same ty = 16 consecutive lanes in a wave)
#pragma unroll
    for (int off = 1; off < 16; off <<= 1) {
#pragma unroll
        for (int m = 0; m < 8; ++m) {
            float ob = __shfl_xor(best[m], off);
            int oi = __shfl_xor(bidx[m], off);
            if (ob < best[m] || (ob == best[m] && oi < bidx[m])) {
                best[m] = ob;
                bidx[m] = oi;
            }
        }
    }
    if (tx == 0) {
#pragma unroll
        for (int m = 0; m < 8; ++m) {
            int row = row0 + ty * 8 + m;
            candB[row * NSPLIT + blockIdx.y] = best[m];
            candI[row * NSPLIT + blockIdx.y] = bidx[m];
        }
    }
}

// ---------------- merge the NSPLIT candidates per row ----------------
__global__ __launch_bounds__(256) void k_merge(const float* __restrict__ candB,
                                               const int* __restrict__ candI,
                                               int* __restrict__ nearest,
                                               float* __restrict__ out1) {
    int row = blockIdx.x * 256 + threadIdx.x;  // grid covers M exactly
    float b = FLT_MAX;
    int bi = 0;
#pragma unroll
    for (int s = 0; s < NSPLIT; ++s) {
        float v = candB[row * NSPLIT + s];
        int i = candI[row * NSPLIT + s];
        if (v < b || (v == b && i < bi)) { b = v; bi = i; }
    }
    nearest[row] = bi;
    out1[row] = (float)bi;
}

// ---------------- scatter: EMA accumulate + commitment loss ----------
__global__ __launch_bounds__(256) void k_scatter(const float* __restrict__ z,
                                                 const float* __restrict__ e,
                                                 const int* __restrict__ nearest,
                                                 float* __restrict__ out3,
                                                 float* __restrict__ out4,
                                                 float* __restrict__ lossAcc) {
    const int tid = threadIdx.x;  // 256 threads, each handles 2 elems/row
    float lp = 0.f;
    const int base_row = blockIdx.x * 8;
#pragma unroll
    for (int r = 0; r < 8; ++r) {
        int row = base_row + r;
        int n = nearest[row];
        float2 zv = ((const float2*)(z + (size_t)row * D_SZ))[tid];
        float2 ev = ((const float2*)(e + (size_t)n * D_SZ))[tid];
        float* o4 = out4 + (size_t)n * D_SZ + tid * 2;
        atomicAdd(o4, OMD_F * zv.x);
        atomicAdd(o4 + 1, OMD_F * zv.y);
        float dx = zv.x - ev.x, dy = zv.y - ev.y;
        lp += dx * dx + dy * dy;
        if (tid == 0) atomicAdd(out3 + n, OMD_F);
    }
#pragma unroll
    for (int off = 32; off; off >>= 1) lp += __shfl_down(lp, off);
    __shared__ float red[4];
    if ((tid & 63) == 0) red[tid >> 6] = lp;
    __syncthreads();
    if (tid == 0) atomicAdd(lossAcc, red[0] + red[1] + red[2] + red[3]);
}

// ---------------- finalize: new_embedding + loss scalar --------------
__global__ __launch_bounds__(256) void k_final(const float* __restrict__ out3,
                                               const float* __restrict__ out4,
                                               float* __restrict__ out5,
                                               const float* __restrict__ lossAcc,
                                               float* __restrict__ out2) {
    int i = blockIdx.x * 256 + threadIdx.x;  // grid covers K*D exactly
    out5[i] = out4[i] / (out3[i >> 9] + EPS_F);
    if (i == 0) out2[0] = 0.25f * lossAcc[0] / 8388608.0f;
}

extern "C" void kernel_launch(void* const* d_in, const int* in_sizes, int n_in,
                              void* d_out, int out_size, void* d_ws, size_t ws_size,
                              hipStream_t stream) {
    const float* z = (const float*)d_in[0];      // encoded_latents (B*N, D)
    const float* ew = (const float*)d_in[1];     // embedding_weight (K, D)
    const float* sizes = (const float*)d_in[2];  // ema_cluster_sizes (K)
    const float* cb = (const float*)d_in[3];     // ema_codebook (K, D)

    float* out = (float*)d_out;
    float* out0 = out;             // quantized_ste == encoded_latents
    float* out1 = out + OUT1_OFF;  // indices (float)
    float* out2 = out + OUT2_OFF;  // loss
    float* out3 = out + OUT3_OFF;  // new_ema_cluster_sizes
    float* out4 = out + OUT4_OFF;  // new_ema_codebook
    float* out5 = out + OUT5_OFF;  // new_embedding

    // small scratch in ws
    int* nearest = (int*)d_ws;                      // 16384 ints
    float* esq = (float*)d_ws + M_SZ;               // 8192 floats
    float* lossAcc = (float*)d_ws + M_SZ + K_SZ;    // 1 float

    // argmin candidates staged in out5 (overwritten by k_final afterwards)
    float* candB = out5;                            // 16384*8 floats
    int* candI = (int*)(out5 + M_SZ * NSPLIT);      // 16384*8 ints

    hipMemsetAsync(lossAcc, 0, sizeof(float), stream);

    k_esq<<<K_SZ / 4, 256, 0, stream>>>(ew, esq);
    k_init<<<(K_SZ * D_SZ) / 256, 256, 0, stream>>>(cb, sizes, out3, out4);
    k_copy<<<(M_SZ * D_SZ / 4) / 256, 256, 0, stream>>>(z, out0);

    dim3 ag(M_SZ / BM, NSPLIT);
    k_argmin<<<ag, 256, 0, stream>>>(z, ew, esq, candB, candI);
    k_merge<<<M_SZ / 256, 256, 0, stream>>>(candB, candI, nearest, out1);
    k_scatter<<<M_SZ / 8, 256, 0, stream>>>(z, ew, nearest, out3, out4, lossAcc);
    k_final<<<(K_SZ * D_SZ) / 256, 256, 0, stream>>>(out3, out4, out5, lossAcc, out2);
}

// Round 4
// 1644.071 us; speedup vs baseline: 1.5582x; 1.0389x over previous
//
#include <hip/hip_runtime.h>
#include <cfloat>

// Problem constants
#define B_SZ 8
#define N_SZ 2048
#define D_SZ 512
#define K_SZ 8192
#define M_SZ (B_SZ * N_SZ)  // 16384

#define DECAY_F 0.99f
#define OMD_F ((float)(1.0 - 0.99))  // one-minus-decay, rounded to f32
#define EPS_F 1e-5f

// Output layout (flat float offsets, reference return order)
#define OUT1_OFF 8388608   // indices (B*N) as float
#define OUT2_OFF 8404992   // commitment loss (1)
#define OUT3_OFF 8404993   // new_ema_cluster_sizes (K)
#define OUT4_OFF 8413185   // new_ema_codebook (K*D)
#define OUT5_OFF 12607489  // new_embedding (K*D)

// Argmin-GEMM tiling
#define BM 128
#define BN 128
#define DKC 32
#define NSPLIT 8
#define KSPLIT (K_SZ / NSPLIT)  // 1024 cols per block
#define CT (KSPLIT / BN)        // 8 col-tiles per block

// ---------------- e_sq: per-codebook-row squared norm ----------------
__global__ __launch_bounds__(256) void k_esq(const float* __restrict__ e,
                                             float* __restrict__ esq) {
    int row = blockIdx.x * 4 + (threadIdx.x >> 6);
    int lane = threadIdx.x & 63;
    const float4* er = (const float4*)(e + (size_t)row * D_SZ);
    float s = 0.f;
#pragma unroll
    for (int i = 0; i < 2; ++i) {
        float4 v = er[lane + i * 64];
        s += v.x * v.x + v.y * v.y + v.z * v.z + v.w * v.w;
    }
#pragma unroll
    for (int off = 32; off; off >>= 1) s += __shfl_down(s, off);
    if (lane == 0) esq[row] = s;
}

// ---------------- init: out4 = 0.99*codebook, out3 = 0.99*sizes ------
__global__ __launch_bounds__(256) void k_init(const float* __restrict__ cb,
                                              const float* __restrict__ sizes,
                                              float* __restrict__ out3,
                                              float* __restrict__ out4) {
    int i = blockIdx.x * 256 + threadIdx.x;  // grid covers K*D exactly
    out4[i] = cb[i] * DECAY_F;
    if (i < K_SZ) out3[i] = sizes[i] * DECAY_F;
}

// ---------------- copy: quantized_ste == encoded_latents -------------
__global__ __launch_bounds__(256) void k_copy(const float* __restrict__ z,
                                              float* __restrict__ out0) {
    int i = blockIdx.x * 256 + threadIdx.x;  // grid covers M*D/4 exactly
    ((float4*)out0)[i] = ((const float4*)z)[i];
}

// ---------------- argmin distance GEMM -------------------------------
// grid = (M/BM, NSPLIT); block = 256 threads; 8x8 accumulators/thread.
// LDS tiles are [k][m] with column XOR-swizzle: phys_col = m ^ (((k>>2)&3)<<3).
//   writes: bank = sm + 8*(tid&3) -> 32 banks x 2 lanes (2-way = free)
//   reads:  kk compile-time -> swizzle constant-folds; a-reads broadcast,
//           b-reads 16x b128 XOR-permuted over 256B (2-way = free)
// NOTE: no min-waves hint — __launch_bounds__(256,4) made the allocator
// spill acc[8][8] to scratch (VGPR=64, WRITE_SIZE 4->288 MB, +1GB FETCH).
__global__ __launch_bounds__(256) void k_argmin(const float* __restrict__ z,
                                                const float* __restrict__ e,
                                                const float* __restrict__ esq,
                                                float* __restrict__ candB,
                                                int* __restrict__ candI) {
    __shared__ float zs[DKC][BM];
    __shared__ float es[DKC][BN];

    const int tid = threadIdx.x;
    const int ty = tid >> 4;   // 0..15 -> 8 rows each
    const int tx = tid & 15;   // 0..15 -> 8 cols each (two groups of 4)
    const int row0 = blockIdx.x * BM;
    const int cbase = blockIdx.y * KSPLIT;

    // staging mapping: thread loads rows sm+32i (i=0..3) at k-offset sk..sk+3
    const int sm = tid >> 3;         // 0..31
    const int sk = (tid & 7) * 4;    // 0,4,..,28
    const int gw = (tid & 3) << 3;   // = ((k>>2)&3)<<3 for k in [sk, sk+3]

    float best[8];
    int bidx[8];
#pragma unroll
    for (int m = 0; m < 8; ++m) { best[m] = FLT_MAX; bidx[m] = 0; }

    for (int ct = 0; ct < CT; ++ct) {
        const int col0 = cbase + ct * BN;
        float acc[8][8];
#pragma unroll
        for (int m = 0; m < 8; ++m)
#pragma unroll
            for (int n = 0; n < 8; ++n) acc[m][n] = 0.f;

        for (int dk = 0; dk < D_SZ / DKC; ++dk) {
            const int d0 = dk * DKC;
            __syncthreads();  // previous compute done reading LDS
#pragma unroll
            for (int i = 0; i < 4; ++i) {
                const int m = sm + 32 * i;
                const int pc = m ^ gw;  // swizzled physical column
                float4 v = *(const float4*)(z + (size_t)(row0 + m) * D_SZ + d0 + sk);
                float4 w = *(const float4*)(e + (size_t)(col0 + m) * D_SZ + d0 + sk);
                zs[sk + 0][pc] = v.x;
                zs[sk + 1][pc] = v.y;
                zs[sk + 2][pc] = v.z;
                zs[sk + 3][pc] = v.w;
                es[sk + 0][pc] = w.x;
                es[sk + 1][pc] = w.y;
                es[sk + 2][pc] = w.z;
                es[sk + 3][pc] = w.w;
            }
            __syncthreads();
            // compute (kk compile-time -> swizzle XORs fold to constants)
#pragma unroll
            for (int kk = 0; kk < DKC; ++kk) {
                const int gr = ((kk >> 2) & 3) << 3;
                float a[8], b[8];
                *(float4*)&a[0] = *(const float4*)&zs[kk][(ty * 8) ^ gr];
                *(float4*)&a[4] = *(const float4*)&zs[kk][(ty * 8 + 4) ^ gr];
                *(float4*)&b[0] = *(const float4*)&es[kk][(tx * 4) ^ gr];
                *(float4*)&b[4] = *(const float4*)&es[kk][(64 + tx * 4) ^ gr];
#pragma unroll
                for (int m = 0; m < 8; ++m)
#pragma unroll
                    for (int n = 0; n < 8; ++n)
                        acc[m][n] = fmaf(a[m], b[n], acc[m][n]);
            }
        }
        // epilogue: dist = e_sq - 2*dot (z_sq row-constant, argmin-invariant)
        // ascending column order within each half; halves are disjoint ranges
#pragma unroll
        for (int h = 0; h < 2; ++h)
#pragma unroll
            for (int n = 0; n < 4; ++n) {
                const int col = col0 + h * 64 + tx * 4 + n;
                const float eq = esq[col];
#pragma unroll
                for (int m = 0; m < 8; ++m) {
                    float dist = fmaf(-2.0f, acc[m][h * 4 + n], eq);
                    if (dist < best[m]) { best[m] = dist; bidx[m] = col; }
                }
            }
    }

    // reduce across the 16 tx lanes (same ty = 16 consecutive lanes in a wave)
#pragma unroll
    for (int off = 1; off < 16; off <<= 1) {
#pragma unroll
        for (int m = 0; m < 8; ++m) {
            float ob = __shfl_xor(best[m], off);
            int oi = __shfl_xor(bidx[m], off);
            if (ob < best[m] || (ob == best[m] && oi < bidx[m])) {
                best[m] = ob;
                bidx[m] = oi;
            }
        }
    }
    if (tx == 0) {
#pragma unroll
        for (int m = 0; m < 8; ++m) {
            int row = row0 + ty * 8 + m;
            candB[row * NSPLIT + blockIdx.y] = best[m];
            candI[row * NSPLIT + blockIdx.y] = bidx[m];
        }
    }
}

// ---------------- merge the NSPLIT candidates per row ----------------
__global__ __launch_bounds__(256) void k_merge(const float* __restrict__ candB,
                                               const int* __restrict__ candI,
                                               int* __restrict__ nearest,
                                               float* __restrict__ out1) {
    int row = blockIdx.x * 256 + threadIdx.x;  // grid covers M exactly
    float b = FLT_MAX;
    int bi = 0;
#pragma unroll
    for (int s = 0; s < NSPLIT; ++s) {
        float v = candB[row * NSPLIT + s];
        int i = candI[row * NSPLIT + s];
        if (v < b || (v == b && i < bi)) { b = v; bi = i; }
    }
    nearest[row] = bi;
    out1[row] = (float)bi;
}

// ---------------- scatter: EMA accumulate + commitment loss ----------
__global__ __launch_bounds__(256) void k_scatter(const float* __restrict__ z,
                                                 const float* __restrict__ e,
                                                 const int* __restrict__ nearest,
                                                 float* __restrict__ out3,
                                                 float* __restrict__ out4,
                                                 float* __restrict__ lossAcc) {
    const int tid = threadIdx.x;  // 256 threads, each handles 2 elems/row
    float lp = 0.f;
    const int base_row = blockIdx.x * 8;
#pragma unroll
    for (int r = 0; r < 8; ++r) {
        int row = base_row + r;
        int n = nearest[row];
        float2 zv = ((const float2*)(z + (size_t)row * D_SZ))[tid];
        float2 ev = ((const float2*)(e + (size_t)n * D_SZ))[tid];
        float* o4 = out4 + (size_t)n * D_SZ + tid * 2;
        atomicAdd(o4, OMD_F * zv.x);
        atomicAdd(o4 + 1, OMD_F * zv.y);
        float dx = zv.x - ev.x, dy = zv.y - ev.y;
        lp += dx * dx + dy * dy;
        if (tid == 0) atomicAdd(out3 + n, OMD_F);
    }
#pragma unroll
    for (int off = 32; off; off >>= 1) lp += __shfl_down(lp, off);
    __shared__ float red[4];
    if ((tid & 63) == 0) red[tid >> 6] = lp;
    __syncthreads();
    if (tid == 0) atomicAdd(lossAcc, red[0] + red[1] + red[2] + red[3]);
}

// ---------------- finalize: new_embedding + loss scalar --------------
__global__ __launch_bounds__(256) void k_final(const float* __restrict__ out3,
                                               const float* __restrict__ out4,
                                               float* __restrict__ out5,
                                               const float* __restrict__ lossAcc,
                                               float* __restrict__ out2) {
    int i = blockIdx.x * 256 + threadIdx.x;  // grid covers K*D exactly
    out5[i] = out4[i] / (out3[i >> 9] + EPS_F);
    if (i == 0) out2[0] = 0.25f * lossAcc[0] / 8388608.0f;
}

extern "C" void kernel_launch(void* const* d_in, const int* in_sizes, int n_in,
                              void* d_out, int out_size, void* d_ws, size_t ws_size,
                              hipStream_t stream) {
    const float* z = (const float*)d_in[0];      // encoded_latents (B*N, D)
    const float* ew = (const float*)d_in[1];     // embedding_weight (K, D)
    const float* sizes = (const float*)d_in[2];  // ema_cluster_sizes (K)
    const float* cb = (const float*)d_in[3];     // ema_codebook (K, D)

    float* out = (float*)d_out;
    float* out0 = out;             // quantized_ste == encoded_latents
    float* out1 = out + OUT1_OFF;  // indices (float)
    float* out2 = out + OUT2_OFF;  // loss
    float* out3 = out + OUT3_OFF;  // new_ema_cluster_sizes
    float* out4 = out + OUT4_OFF;  // new_ema_codebook
    float* out5 = out + OUT5_OFF;  // new_embedding

    // small scratch in ws
    int* nearest = (int*)d_ws;                      // 16384 ints
    float* esq = (float*)d_ws + M_SZ;               // 8192 floats
    float* lossAcc = (float*)d_ws + M_SZ + K_SZ;    // 1 float

    // argmin candidates staged in out5 (overwritten by k_final afterwards)
    float* candB = out5;                            // 16384*8 floats
    int* candI = (int*)(out5 + M_SZ * NSPLIT);      // 16384*8 ints

    hipMemsetAsync(lossAcc, 0, sizeof(float), stream);

    k_esq<<<K_SZ / 4, 256, 0, stream>>>(ew, esq);
    k_init<<<(K_SZ * D_SZ) / 256, 256, 0, stream>>>(cb, sizes, out3, out4);
    k_copy<<<(M_SZ * D_SZ / 4) / 256, 256, 0, stream>>>(z, out0);

    dim3 ag(M_SZ / BM, NSPLIT);
    k_argmin<<<ag, 256, 0, stream>>>(z, ew, esq, candB, candI);
    k_merge<<<M_SZ / 256, 256, 0, stream>>>(candB, candI, nearest, out1);
    k_scatter<<<M_SZ / 8, 256, 0, stream>>>(z, ew, nearest, out3, out4, lossAcc);
    k_final<<<(K_SZ * D_SZ) / 256, 256, 0, stream>>>(out3, out4, out5, lossAcc, out2);
}

// Round 5
// 859.758 us; speedup vs baseline: 2.9797x; 1.9122x over previous
//
#include <hip/hip_runtime.h>
#include <cfloat>

// Problem constants
#define B_SZ 8
#define N_SZ 2048
#define D_SZ 512
#define K_SZ 8192
#define M_SZ (B_SZ * N_SZ)  // 16384

#define DECAY_F 0.99f
#define OMD_F ((float)(1.0 - 0.99))
#define EPS_F 1e-5f

// Output layout (flat float offsets, reference return order)
#define OUT1_OFF 8388608   // indices (B*N) as float
#define OUT2_OFF 8404992   // commitment loss (1)
#define OUT3_OFF 8404993   // new_ema_cluster_sizes (K)
#define OUT4_OFF 8413185   // new_ema_codebook (K*D)
#define OUT5_OFF 12607489  // new_embedding (K*D)

typedef unsigned short ushort_t;
typedef unsigned int uint_t;
typedef short bf16x8 __attribute__((ext_vector_type(8)));
typedef float f32x4 __attribute__((ext_vector_type(4)));

// ---- manual RTNE fp32 -> bf16 ----
__device__ inline ushort_t f2bf(float v) {
    union { float f; uint_t u; } x; x.f = v;
    uint_t r = x.u + 0x7FFFu + ((x.u >> 16) & 1u);
    return (ushort_t)(r >> 16);
}
__device__ inline float bf2f(ushort_t h) {
    union { float f; uint_t u; } x; x.u = ((uint_t)h) << 16; return x.f;
}

// ---------------- e_sq ----------------
__global__ __launch_bounds__(256) void k_esq(const float* __restrict__ e,
                                             float* __restrict__ esq) {
    int row = blockIdx.x * 4 + (threadIdx.x >> 6);
    int lane = threadIdx.x & 63;
    const float4* er = (const float4*)(e + (size_t)row * D_SZ);
    float s = 0.f;
#pragma unroll
    for (int i = 0; i < 2; ++i) {
        float4 v = er[lane + i * 64];
        s += v.x * v.x + v.y * v.y + v.z * v.z + v.w * v.w;
    }
#pragma unroll
    for (int off = 32; off; off >>= 1) s += __shfl_down(s, off);
    if (lane == 0) esq[row] = s;
}

// ---------------- bf16 two-plane split: x = h1 + h2 + O(2^-18) ------
__global__ __launch_bounds__(256) void k_split(const float* __restrict__ in,
                                               ushort_t* __restrict__ h1,
                                               ushort_t* __restrict__ h2) {
    size_t i = ((size_t)blockIdx.x * 256 + threadIdx.x) * 8;
    float4 a = *(const float4*)(in + i);
    float4 b = *(const float4*)(in + i + 4);
    float vv[8] = {a.x, a.y, a.z, a.w, b.x, b.y, b.z, b.w};
    ushort_t o1[8], o2[8];
#pragma unroll
    for (int j = 0; j < 8; ++j) {
        ushort_t p = f2bf(vv[j]);
        o1[j] = p;
        o2[j] = f2bf(vv[j] - bf2f(p));
    }
    *(uint4*)(h1 + i) = *(uint4*)o1;
    *(uint4*)(h2 + i) = *(uint4*)o2;
}

// ---------------- init / copy / final / scatter (unchanged math) ----
__global__ __launch_bounds__(256) void k_init(const float* __restrict__ cb,
                                              const float* __restrict__ sizes,
                                              float* __restrict__ out3,
                                              float* __restrict__ out4) {
    int i = blockIdx.x * 256 + threadIdx.x;
    out4[i] = cb[i] * DECAY_F;
    if (i < K_SZ) out3[i] = sizes[i] * DECAY_F;
}

__global__ __launch_bounds__(256) void k_copy(const float* __restrict__ z,
                                              float* __restrict__ out0) {
    int i = blockIdx.x * 256 + threadIdx.x;
    ((float4*)out0)[i] = ((const float4*)z)[i];
}

__global__ __launch_bounds__(256) void k_scatter(const float* __restrict__ z,
                                                 const float* __restrict__ e,
                                                 const int* __restrict__ nearest,
                                                 float* __restrict__ out3,
                                                 float* __restrict__ out4,
                                                 float* __restrict__ lossAcc) {
    const int tid = threadIdx.x;
    float lp = 0.f;
    const int base_row = blockIdx.x * 8;
#pragma unroll
    for (int r = 0; r < 8; ++r) {
        int row = base_row + r;
        int n = nearest[row];
        float2 zv = ((const float2*)(z + (size_t)row * D_SZ))[tid];
        float2 ev = ((const float2*)(e + (size_t)n * D_SZ))[tid];
        float* o4 = out4 + (size_t)n * D_SZ + tid * 2;
        atomicAdd(o4, OMD_F * zv.x);
        atomicAdd(o4 + 1, OMD_F * zv.y);
        float dx = zv.x - ev.x, dy = zv.y - ev.y;
        lp += dx * dx + dy * dy;
        if (tid == 0) atomicAdd(out3 + n, OMD_F);
    }
#pragma unroll
    for (int off = 32; off; off >>= 1) lp += __shfl_down(lp, off);
    __shared__ float red[4];
    if ((tid & 63) == 0) red[tid >> 6] = lp;
    __syncthreads();
    if (tid == 0) atomicAdd(lossAcc, red[0] + red[1] + red[2] + red[3]);
}

__global__ __launch_bounds__(256) void k_final(const float* __restrict__ out3,
                                               const float* __restrict__ out4,
                                               float* __restrict__ out5,
                                               const float* __restrict__ lossAcc,
                                               float* __restrict__ out2) {
    int i = blockIdx.x * 256 + threadIdx.x;
    out5[i] = out4[i] / (out3[i >> 9] + EPS_F);
    if (i == 0) out2[0] = 0.25f * lossAcc[0] / 8388608.0f;
}

// ---------------- pass 1: 3-term bf16 MFMA distance + per-list top2 --
// grid 1024: s = b&7 (code range s*1024, pins e-slice to one XCD's L2),
//            zb = b>>3 (128 zrows). 512 threads = 8 waves (4m x 2n),
// wave tile 64 codes x 64 zrows, MFMA 16x16x32 bf16 (A=e, B=z swapped:
// D[m=code][n=zrow], C/D row=(l>>4)*4+reg, col=l&15  [m89/m91 layouts]).
// LDS rows: [row][pl(2)][k32] = 128B, slot s=pl*4+g XOR (row&7) swizzle.
__global__ __launch_bounds__(512) void k_pass1(const ushort_t* __restrict__ zh1,
                                               const ushort_t* __restrict__ zh2,
                                               const ushort_t* __restrict__ eh1,
                                               const ushort_t* __restrict__ eh2,
                                               const float* __restrict__ esq,
                                               float* __restrict__ candD,
                                               int* __restrict__ candI) {
    __shared__ uint_t e_lds[256 * 32];  // 32 KB
    __shared__ uint_t z_lds[128 * 32];  // 16 KB

    const int tid = threadIdx.x;
    const int lane = tid & 63;
    const int wv = tid >> 6;            // 0..7
    const int mw = wv >> 1;             // 0..3 (code wave-row)
    const int nw = wv & 1;              // 0..1 (zrow wave-col)
    const int lr = lane & 15;           // frag row / D col
    const int g = lane >> 4;            // k-group / D row-group

    const int s = blockIdx.x & 7;
    const int zb = blockIdx.x >> 3;
    const int cbase = s * 1024;
    const int zrow0 = zb * 128;

    const ushort_t* zh[2] = {zh1, zh2};
    const ushort_t* eh[2] = {eh1, eh2};

    float b1[4], b2[4];
    int i1[4], i2[4];
#pragma unroll
    for (int nf = 0; nf < 4; ++nf) {
        b1[nf] = FLT_MAX; b2[nf] = FLT_MAX;
        i1[nf] = 0x7fffffff; i2[nf] = 0x7fffffff;
    }

    for (int it = 0; it < 4; ++it) {
        const int code0 = cbase + it * 256;
        f32x4 acc[4][4];
#pragma unroll
        for (int mf = 0; mf < 4; ++mf)
#pragma unroll
            for (int nf = 0; nf < 4; ++nf)
                acc[mf][nf] = (f32x4){0.f, 0.f, 0.f, 0.f};

        for (int ch = 0; ch < 16; ++ch) {
            const int k0 = ch * 32;
            __syncthreads();
            // stage e: 2048 16B pieces (256 rows x {pl,g})
#pragma unroll
            for (int i = 0; i < 4; ++i) {
                int p = tid + i * 512;
                int row = p >> 3, sp = p & 7;
                int pl = sp >> 2, gg = sp & 3;
                uint4 v = *(const uint4*)(eh[pl] + (size_t)(code0 + row) * D_SZ + k0 + gg * 8);
                *(uint4*)&e_lds[row * 32 + ((sp ^ (row & 7)) << 2)] = v;
            }
            // stage z: 1024 pieces (128 rows)
#pragma unroll
            for (int i = 0; i < 2; ++i) {
                int p = tid + i * 512;
                int row = p >> 3, sp = p & 7;
                int pl = sp >> 2, gg = sp & 3;
                uint4 v = *(const uint4*)(zh[pl] + (size_t)(zrow0 + row) * D_SZ + k0 + gg * 8);
                *(uint4*)&z_lds[row * 32 + ((sp ^ (row & 7)) << 2)] = v;
            }
            __syncthreads();

            // z-frags: 4 n-frags x 2 planes
            bf16x8 zf[4][2];
#pragma unroll
            for (int nf = 0; nf < 4; ++nf)
#pragma unroll
                for (int pl = 0; pl < 2; ++pl) {
                    int row = nw * 64 + nf * 16 + lr;
                    int sl = (pl * 4 + g) ^ (row & 7);
                    zf[nf][pl] = *(const bf16x8*)&z_lds[row * 32 + (sl << 2)];
                }
#pragma unroll
            for (int mf = 0; mf < 4; ++mf) {
                bf16x8 ef[2];
                int row = mw * 64 + mf * 16 + lr;
#pragma unroll
                for (int pl = 0; pl < 2; ++pl) {
                    int sl = (pl * 4 + g) ^ (row & 7);
                    ef[pl] = *(const bf16x8*)&e_lds[row * 32 + (sl << 2)];
                }
#pragma unroll
                for (int nf = 0; nf < 4; ++nf) {
                    acc[mf][nf] = __builtin_amdgcn_mfma_f32_16x16x32_bf16(ef[0], zf[nf][0], acc[mf][nf], 0, 0, 0);
                    acc[mf][nf] = __builtin_amdgcn_mfma_f32_16x16x32_bf16(ef[1], zf[nf][0], acc[mf][nf], 0, 0, 0);
                    acc[mf][nf] = __builtin_amdgcn_mfma_f32_16x16x32_bf16(ef[0], zf[nf][1], acc[mf][nf], 0, 0, 0);
                }
            }
        }
        // epilogue: dist = esq - 2*dot; update per-zrow top2
#pragma unroll
        for (int mf = 0; mf < 4; ++mf)
#pragma unroll
            for (int r = 0; r < 4; ++r) {
                int code = code0 + mw * 64 + mf * 16 + g * 4 + r;
                float eq = esq[code];
#pragma unroll
                for (int nf = 0; nf < 4; ++nf) {
                    float d = fmaf(-2.f, acc[mf][nf][r], eq);
                    if (d < b1[nf]) {
                        b2[nf] = b1[nf]; i2[nf] = i1[nf];
                        b1[nf] = d; i1[nf] = code;
                    } else if (d < b2[nf]) {
                        b2[nf] = d; i2[nf] = code;
                    }
                }
            }
    }

    // merge top2 across the 4 k-groups holding the same zrow (xor 16, 32)
#pragma unroll
    for (int off = 16; off <= 32; off <<= 1) {
#pragma unroll
        for (int nf = 0; nf < 4; ++nf) {
            float ob1 = __shfl_xor(b1[nf], off); int oi1 = __shfl_xor(i1[nf], off);
            float ob2 = __shfl_xor(b2[nf], off); int oi2 = __shfl_xor(i2[nf], off);
            bool tA = (b1[nf] < ob1) || (b1[nf] == ob1 && i1[nf] <= oi1);
            float n1 = tA ? b1[nf] : ob1; int ni1 = tA ? i1[nf] : oi1;
            float ca = tA ? b2[nf] : ob2; int cia = tA ? i2[nf] : oi2;
            float cb = tA ? ob1 : b1[nf]; int cib = tA ? oi1 : i1[nf];
            bool t2 = (ca < cb) || (ca == cb && cia <= cib);
            b1[nf] = n1; i1[nf] = ni1;
            b2[nf] = t2 ? ca : cb; i2[nf] = t2 ? cia : cib;
        }
    }
    if (g == 0) {
        const int list = s * 4 + mw;  // 0..31
#pragma unroll
        for (int nf = 0; nf < 4; ++nf) {
            int row = zrow0 + nw * 64 + nf * 16 + lr;
            size_t base = (size_t)row * 64 + list * 2;
            candD[base] = b1[nf]; candD[base + 1] = b2[nf];
            candI[base] = i1[nf]; candI[base + 1] = i2[nf];
        }
    }
}

// ---------------- refine: exact fp32 re-rank of merged top-4 ---------
__global__ __launch_bounds__(256) void k_refine(const float* __restrict__ z,
                                                const float* __restrict__ e,
                                                const float* __restrict__ esq,
                                                const float* __restrict__ candD,
                                                const int* __restrict__ candI,
                                                int* __restrict__ nearest,
                                                float* __restrict__ out1) {
    const int lane = threadIdx.x & 63;
    const int row = blockIdx.x * 4 + (threadIdx.x >> 6);

    const float4* zr = (const float4*)(z + (size_t)row * D_SZ + lane * 8);
    float4 za = zr[0], zb = zr[1];
    float zsq = za.x * za.x + za.y * za.y + za.z * za.z + za.w * za.w +
                zb.x * zb.x + zb.y * zb.y + zb.z * zb.z + zb.w * zb.w;
#pragma unroll
    for (int off = 32; off; off >>= 1) zsq += __shfl_xor(zsq, off);

    float d = candD[(size_t)row * 64 + lane];
    int ci = candI[(size_t)row * 64 + lane];

    float best = FLT_MAX;
    int bidx = 0x7fffffff;
#pragma unroll
    for (int c = 0; c < 4; ++c) {
        float md = d; int mi = ci;
#pragma unroll
        for (int off = 32; off; off >>= 1) {
            float od = __shfl_xor(md, off); int oi = __shfl_xor(mi, off);
            if (od < md || (od == md && oi < mi)) { md = od; mi = oi; }
        }
        if (ci == mi) d = FLT_MAX;  // codes unique across lanes
        // exact fp32 distance for candidate mi
        const float4* er = (const float4*)(e + (size_t)mi * D_SZ + lane * 8);
        float4 ea = er[0], eb = er[1];
        float dot = za.x * ea.x + za.y * ea.y + za.z * ea.z + za.w * ea.w +
                    zb.x * eb.x + zb.y * eb.y + zb.z * eb.z + zb.w * eb.w;
#pragma unroll
        for (int off = 32; off; off >>= 1) dot += __shfl_xor(dot, off);
        float dex = (zsq - 2.f * dot) + esq[mi];
        if (dex < best || (dex == best && mi < bidx)) { best = dex; bidx = mi; }
    }
    if (lane == 0) {
        nearest[row] = bidx;
        out1[row] = (float)bidx;
    }
}

extern "C" void kernel_launch(void* const* d_in, const int* in_sizes, int n_in,
                              void* d_out, int out_size, void* d_ws, size_t ws_size,
                              hipStream_t stream) {
    const float* z = (const float*)d_in[0];
    const float* ew = (const float*)d_in[1];
    const float* sizes = (const float*)d_in[2];
    const float* cb = (const float*)d_in[3];

    float* out = (float*)d_out;
    float* out0 = out;
    float* out1 = out + OUT1_OFF;
    float* out2 = out + OUT2_OFF;
    float* out3 = out + OUT3_OFF;
    float* out4 = out + OUT4_OFF;
    float* out5 = out + OUT5_OFF;

    // ws scratch (small)
    int* nearest = (int*)d_ws;
    float* esq = (float*)d_ws + M_SZ;
    float* lossAcc = (float*)d_ws + M_SZ + K_SZ;

    // plane/candidate scratch inside d_out (consumed before overwritten):
    // z-planes fill out0 exactly (32 MB); e-planes + cands live in the
    // contiguous out4+out5 region (32 MB), 16B-aligned at +12 bytes.
    ushort_t* zh1 = (ushort_t*)out0;
    ushort_t* zh2 = zh1 + (size_t)M_SZ * D_SZ;
    unsigned char* s4 = (unsigned char*)out4 + 12;
    ushort_t* eh1 = (ushort_t*)s4;
    ushort_t* eh2 = eh1 + (size_t)K_SZ * D_SZ;
    float* candD = (float*)(s4 + 16777216);
    int* candI = (int*)(s4 + 16777216 + 4194304);

    hipMemsetAsync(lossAcc, 0, sizeof(float), stream);

    k_esq<<<K_SZ / 4, 256, 0, stream>>>(ew, esq);
    k_split<<<(M_SZ * D_SZ / 8) / 256, 256, 0, stream>>>(z, zh1, zh2);
    k_split<<<(K_SZ * D_SZ / 8) / 256, 256, 0, stream>>>(ew, eh1, eh2);

    k_pass1<<<1024, 512, 0, stream>>>(zh1, zh2, eh1, eh2, esq, candD, candI);
    k_refine<<<M_SZ / 4, 256, 0, stream>>>(z, ew, esq, candD, candI, nearest, out1);

    // now safe to overwrite scratch regions with real outputs
    k_init<<<(K_SZ * D_SZ) / 256, 256, 0, stream>>>(cb, sizes, out3, out4);
    k_copy<<<(M_SZ * D_SZ / 4) / 256, 256, 0, stream>>>(z, out0);
    k_scatter<<<M_SZ / 8, 256, 0, stream>>>(z, ew, nearest, out3, out4, lossAcc);
    k_final<<<(K_SZ * D_SZ) / 256, 256, 0, stream>>>(out3, out4, out5, lossAcc, out2);
}